// Round 4
// baseline (851.803 us; speedup 1.0000x reference)
//
#include <hip/hip_runtime.h>
#include <math.h>

#define TOKENS  32768
#define HIDDEN  2048
#define EXPERTS 64
#define TOPK    8
#define TBLK    16                  // tokens per block (and per wave)
#define KSPLIT  4                   // waves per block, splitting K
#define KSLICE  (HIDDEN / KSPLIT)   // 512 k per wave

// ---------------------------------------------------------------------------
// Kernel 1: transpose weight [64][2048] -> wT [2048][64] so that per-k the 64
// expert weights are consecutive -> one coalesced dword/lane (lane = expert).
// ---------------------------------------------------------------------------
__global__ void wt_transpose(const float* __restrict__ W, float* __restrict__ wT) {
    int i = blockIdx.x * 256 + threadIdx.x;   // 0..131071
    int k = i >> 6;
    int e = i & 63;
    wT[i] = W[e * HIDDEN + k];
}

// ---------------------------------------------------------------------------
// Kernel 2: fused router. Block = 256 thr = 4 waves; block owns 16 tokens.
// lane = expert (0..63); wave w owns k in [w*512, w*512+512).
// Per k: W via coalesced global dword (lane=e), A via wave-uniform s_load
// (float2, double-buffered in SGPRs); 16 v_fmac(acc[t], s_a, v_w).
// acc = 16 VGPR -> ~30 VGPR total -> 8 waves/SIMD, 32 waves/CU.
// Epilogue: LDS reduce over 4 waves + bias, per-token top-8 + softmax +
// scatter, coalesced writes. Indices stored as float values.
// ---------------------------------------------------------------------------
__global__ __launch_bounds__(256, 8)
void router_sv(const float* __restrict__ A,
               const float* __restrict__ wT,
               const float* __restrict__ bias,
               float* __restrict__ out) {
    __shared__ float lds[4160];   // [0..3071] partials / later scat; [3072..4159] logits [16][68]
    const int tid  = threadIdx.x;
    const int w    = __builtin_amdgcn_readfirstlane(tid >> 6);  // wave-uniform for scalar addressing
    const int lane = tid & 63;                                  // expert
    const int g    = blockIdx.x;                                // token group

    const int k0 = w * KSLICE;
    // wave-uniform A base: 16 token rows, row t at constant offset t*HIDDEN
    const float* abase = A + (size_t)g * TBLK * HIDDEN + k0;
    // per-lane W stream: wT[(k0+kk)*64 + lane]
    const float* wp = wT + (size_t)k0 * 64 + lane;

    float acc[TBLK];
    #pragma unroll
    for (int t = 0; t < TBLK; ++t) acc[t] = 0.f;

    // ---- prime: A chunk 0 (2 k's per row, scalar float2) + W k0,k0+1 ----
    float2 a_cur[TBLK], a_nxt[TBLK];
    #pragma unroll
    for (int t = 0; t < TBLK; ++t)
        a_cur[t] = *(const float2*)(abase + t * HIDDEN);
    float w0 = wp[0];
    float w1 = wp[64];

    #pragma unroll 2
    for (int c = 0; c < KSLICE / 2; ++c) {
        const int kk = 2 * c;
        float w2 = 0.f, w3 = 0.f;
        if (c + 1 < KSLICE / 2) {
            // prefetch next chunk: A (scalar) and W (vector)
            #pragma unroll
            for (int t = 0; t < TBLK; ++t)
                a_nxt[t] = *(const float2*)(abase + t * HIDDEN + kk + 2);
            w2 = wp[(kk + 2) * 64];
            w3 = wp[(kk + 3) * 64];
        }
        #pragma unroll
        for (int t = 0; t < TBLK; ++t) acc[t] = fmaf(a_cur[t].x, w0, acc[t]);
        #pragma unroll
        for (int t = 0; t < TBLK; ++t) acc[t] = fmaf(a_cur[t].y, w1, acc[t]);
        #pragma unroll
        for (int t = 0; t < TBLK; ++t) a_cur[t] = a_nxt[t];
        w0 = w2; w1 = w3;
    }

    // ---- reduce 4 waves via LDS: waves 1-3 dump, wave 0 sums ----
    if (w > 0) {
        #pragma unroll
        for (int t = 0; t < TBLK; ++t)
            lds[(w - 1) * 1024 + t * 64 + lane] = acc[t];
    }
    __syncthreads();
    if (w == 0) {
        float b = bias[lane];
        #pragma unroll
        for (int t = 0; t < TBLK; ++t) {
            float v = acc[t] + lds[t * 64 + lane]
                             + lds[1024 + t * 64 + lane]
                             + lds[2048 + t * 64 + lane] + b;
            lds[3072 + t * 68 + lane] = v;    // logits [t][68] padded
        }
    }
    __syncthreads();

    // zero scatter area (aliases partials region, all reads done)
    for (int i = tid; i < TBLK * 65; i += 256) lds[i] = 0.f;
    __syncthreads();

    // ---- top-8 + softmax + scatter: one thread per token ----
    if (tid < TBLK) {
        const int t = tid;
        float v[64];
        #pragma unroll
        for (int e4 = 0; e4 < 16; ++e4) {
            float4 q = *(const float4*)(&lds[3072 + t * 68 + e4 * 4]);
            v[e4 * 4 + 0] = q.x; v[e4 * 4 + 1] = q.y;
            v[e4 * 4 + 2] = q.z; v[e4 * 4 + 3] = q.w;
        }
        float tvals[TOPK]; int tix[TOPK]; float probs[TOPK];
        unsigned long long chosen = 0ull;
        #pragma unroll
        for (int j = 0; j < TOPK; ++j) {
            float best = -INFINITY; int bi = 0;
            #pragma unroll
            for (int e = 0; e < 64; ++e) {
                bool ok = ((chosen >> e) & 1ull) == 0ull;
                if (ok && v[e] > best) { best = v[e]; bi = e; }  // strict >: lowest idx on tie
            }
            chosen |= (1ull << bi);
            tvals[j] = best; tix[j] = bi;
        }
        float m = tvals[0];
        float s = 0.f;
        #pragma unroll
        for (int j = 0; j < TOPK; ++j) { probs[j] = __expf(tvals[j] - m); s += probs[j]; }
        float inv = 1.f / s;
        #pragma unroll
        for (int j = 0; j < TOPK; ++j) probs[j] *= inv;

        #pragma unroll
        for (int j = 0; j < TOPK; ++j) lds[t * 65 + tix[j]] = probs[j];

        float* oidx = out + (size_t)TOKENS * EXPERTS;
        const int token = g * TBLK + t;
        #pragma unroll
        for (int j = 0; j < TOPK; ++j) oidx[(size_t)token * TOPK + j] = (float)tix[j];
    }
    __syncthreads();

    // ---- coalesced score write: 16 tokens x 64 experts = 256 float4 ----
    {
        int tok = tid >> 4;
        int e4  = (tid & 15) * 4;
        float4 vv;
        vv.x = lds[tok * 65 + e4 + 0];
        vv.y = lds[tok * 65 + e4 + 1];
        vv.z = lds[tok * 65 + e4 + 2];
        vv.w = lds[tok * 65 + e4 + 3];
        *(float4*)(out + (size_t)g * TBLK * 64 + (size_t)tid * 4) = vv;
    }
}

extern "C" void kernel_launch(void* const* d_in, const int* in_sizes, int n_in,
                              void* d_out, int out_size, void* d_ws, size_t ws_size,
                              hipStream_t stream) {
    const float* A    = (const float*)d_in[0];   // [32768, 2048] fp32
    const float* W    = (const float*)d_in[1];   // [64, 2048] fp32
    const float* bias = (const float*)d_in[2];   // [64] fp32
    float* out = (float*)d_out;                  // scores (32768*64) ++ idx (32768*8)
    float* wT  = (float*)d_ws;                   // 512 KB scratch

    wt_transpose<<<512, 256, 0, stream>>>(W, wT);
    router_sv<<<TOKENS / TBLK, 256, 0, stream>>>(A, wT, bias, out);
}